// Round 4
// baseline (106.198 us; speedup 1.0000x reference)
//
#include <hip/hip_runtime.h>
#include <hip/hip_bf16.h>

#define NROWS 4096
#define DDIM  256
#define EPS   1e-8f
// Normalized rows are scaled by sqrt(2*log2(e)) so the MFMA dot product IS the
// exp2 argument: exp2(<se_i, se_j>) = exp(<e_i,e_j>/T), T = 0.5.
#define SCALE 1.69864944f
#define LN2   0.69314718056f

#define NJ 32          // j-slices (grid.y)
#define JS 256         // cols per slice
#define BT 64          // cols per staged LDS chunk
#define CH (JS / BT)   // 4 chunks per slice
// LDS fragment-ordered: [buf][cgrp(4)][ks(8)][lane(64)][8 shorts] = 32 KB/buf
#define BUFSH (4 * 8 * 64 * 8)

typedef __attribute__((ext_vector_type(8))) short short8;
typedef __attribute__((ext_vector_type(4))) float f32x4;

#if __has_builtin(__builtin_amdgcn_exp2f)
#define EXP2F(x) __builtin_amdgcn_exp2f(x)
#else
#define EXP2F(x) exp2f(x)
#endif

__device__ __forceinline__ unsigned short f2bf(float x) {
    union { __hip_bfloat16 h; unsigned short u; } c;
    c.h = __float2bfloat16(x);
    return c.u;
}
__device__ __forceinline__ float bf2f(unsigned short u) {
    union { unsigned int i; float f; } c;
    c.i = ((unsigned int)u) << 16;
    return c.f;
}

// ---------------------------------------------------------------------------
// Kernel 1: row L2-normalize fp32 -> scaled bf16; zero S / cell / counter.
// One wave per row: grid = 2N/4 blocks x 256 threads.
__global__ void normalize_kernel(const float* __restrict__ a,
                                 const float* __restrict__ b,
                                 unsigned short* __restrict__ en,
                                 float* __restrict__ S,
                                 float* __restrict__ cell,
                                 unsigned int* __restrict__ counter, int N) {
    const int wave = threadIdx.x >> 6, lane = threadIdx.x & 63;
    const int row = blockIdx.x * 4 + wave;
    const float* src = (row < N) ? (a + (size_t)row * DDIM)
                                 : (b + (size_t)(row - N) * DDIM);
    const float4 v = reinterpret_cast<const float4*>(src)[lane];
    float ss = v.x * v.x + v.y * v.y + v.z * v.z + v.w * v.w;
    #pragma unroll
    for (int off = 32; off > 0; off >>= 1) ss += __shfl_xor(ss, off);
    const float inv = SCALE / fmaxf(sqrtf(ss), EPS * SCALE);
    ushort4 o;
    o.x = f2bf(v.x * inv);
    o.y = f2bf(v.y * inv);
    o.z = f2bf(v.z * inv);
    o.w = f2bf(v.w * inv);
    *reinterpret_cast<ushort4*>(en + (size_t)row * DDIM + lane * 4) = o;
    if (lane == 0 && row < N) S[row] = 0.0f;
    if (blockIdx.x == 0 && threadIdx.x == 0) { *cell = 0.0f; *counter = 0u; }
}

// ---------------------------------------------------------------------------
// Kernel 2: UNMASKED exp2 row-sums via MFMA (diagonal-family terms are
// corrected later in loss_kernel). grid = (16 i-blocks of 256 rows, NJ
// j-slices), block = 256 (4 waves). Each wave holds 64 A-rows register-
// resident (128 VGPRs); B double-buffered in LDS via async global_load_lds
// (fragment order, lane*16B).
// MFMA 16x16x32 bf16 verified layouts:
//   A/B operand: elem j of lane l = M[base + (l&15)][ks*32 + (l>>4)*8 + j]
//   C/D:         reg r of lane l  = C[(l>>4)*4 + r][l&15]
__global__ __launch_bounds__(256, 2) void simsum_kernel(
        const short* __restrict__ en,
        float* __restrict__ S) {
    __shared__ short bt[2 * BUFSH];
    const int tid = threadIdx.x;
    const int wave = tid >> 6, lane = tid & 63;
    const int lrow = lane & 15, quad = lane >> 4;
    const int i0 = blockIdx.x * 256 + wave * 64;
    const int jb = blockIdx.y * JS;

    // Async stage of one 64-col chunk: wave w stages row-group w (16 cols),
    // all 8 k-steps. DMA writes LDS at uniform base + lane*16B == fragment
    // order for the consuming ds_read_b128.
    auto stage = [&](int jc, int buf) {
        const short* g = en + (size_t)(jc + wave * 16 + lrow) * DDIM + quad * 8;
        short* l = bt + buf * BUFSH + wave * 4096;
        #pragma unroll
        for (int ks = 0; ks < 8; ++ks) {
            __builtin_amdgcn_global_load_lds(
                (const __attribute__((address_space(1))) void*)(g + ks * 32),
                (__attribute__((address_space(3))) void*)(l + ks * 512),
                16, 0, 0);
        }
    };

    // Issue first stage BEFORE the A-frag loads so its latency hides there.
    stage(jb, 0);

    // A fragments: 4 row-tiles x K=256, register-resident for the kernel.
    short8 afrag[4][8];
    #pragma unroll
    for (int t = 0; t < 4; ++t)
        #pragma unroll
        for (int ks = 0; ks < 8; ++ks)
            afrag[t][ks] = *reinterpret_cast<const short8*>(
                en + (size_t)(i0 + t * 16 + lrow) * DDIM + ks * 32 + quad * 8);

    float rowsum[4][4];
    #pragma unroll
    for (int t = 0; t < 4; ++t)
        #pragma unroll
        for (int r = 0; r < 4; ++r) rowsum[t][r] = 0.0f;

    for (int c = 0; c < CH; ++c) {
        __syncthreads();                     // chunk c staged; prev readers done
        if (c + 1 < CH) stage(jb + (c + 1) * BT, (c + 1) & 1);
        const short* lb = bt + (c & 1) * BUFSH;
        #pragma unroll
        for (int cg = 0; cg < 4; ++cg) {
            f32x4 acc[4];
            #pragma unroll
            for (int t = 0; t < 4; ++t) acc[t] = f32x4{0.f, 0.f, 0.f, 0.f};
            #pragma unroll
            for (int ks = 0; ks < 8; ++ks) {
                const short8 bfrag = *reinterpret_cast<const short8*>(
                    lb + cg * 4096 + ks * 512 + lane * 8);
                #pragma unroll
                for (int t = 0; t < 4; ++t)
                    acc[t] = __builtin_amdgcn_mfma_f32_16x16x32_bf16(
                        afrag[t][ks], bfrag, acc[t], 0, 0, 0);
            }
            // Mask-free epilogue: 16 exp2 + 16 adds, no branches.
            #pragma unroll
            for (int t = 0; t < 4; ++t)
                #pragma unroll
                for (int r = 0; r < 4; ++r)
                    rowsum[t][r] += EXP2F(acc[t][r]);
        }
    }

    // Reduce each rowsum over the 16 lanes sharing a quad, then one atomic.
    #pragma unroll
    for (int t = 0; t < 4; ++t) {
        #pragma unroll
        for (int r = 0; r < 4; ++r) {
            float v = rowsum[t][r];
            v += __shfl_xor(v, 1);
            v += __shfl_xor(v, 2);
            v += __shfl_xor(v, 4);
            v += __shfl_xor(v, 8);
            rowsum[t][r] = v;
        }
        if (lrow < 4) {
            const float v = (lrow == 0) ? rowsum[t][0]
                          : (lrow == 1) ? rowsum[t][1]
                          : (lrow == 2) ? rowsum[t][2]
                          :               rowsum[t][3];
            atomicAdd(&S[i0 + t * 16 + quad * 4 + lrow], v);
        }
    }
}

// ---------------------------------------------------------------------------
// Kernel 3: per-row diagonal corrections + final loss.
// grid = 64 blocks x 256 threads; wave gw handles rows gw*16..gw*16+15.
// For each row: selfdot = <se_i,se_i>, posdot = <se_i,se_{N+i}> in fp32
// (matches the MFMA values to ~1e-6). Then
//   contrib_i = pos_i - ln(S_i - exp2(selfdot) - exp2(posdot)),
// with pos_i = posdot*ln2. Last block (atomic counter) writes the mean.
__global__ void loss_kernel(const unsigned short* __restrict__ en,
                            const float* __restrict__ S,
                            float* __restrict__ cell,
                            unsigned int* __restrict__ counter,
                            float* __restrict__ out, int N) {
    const int tid = threadIdx.x;
    const int wave = tid >> 6, lane = tid & 63;
    const int gw = blockIdx.x * 4 + wave;          // 0..255
    float wacc = 0.0f;
    for (int rr = 0; rr < 16; ++rr) {
        const int row = gw * 16 + rr;
        const ushort4 ua = *reinterpret_cast<const ushort4*>(
            en + (size_t)row * DDIM + lane * 4);
        const ushort4 ub = *reinterpret_cast<const ushort4*>(
            en + (size_t)(N + row) * DDIM + lane * 4);
        const float a0 = bf2f(ua.x), a1 = bf2f(ua.y),
                    a2 = bf2f(ua.z), a3 = bf2f(ua.w);
        const float b0 = bf2f(ub.x), b1 = bf2f(ub.y),
                    b2 = bf2f(ub.z), b3 = bf2f(ub.w);
        float sd = a0 * a0 + a1 * a1 + a2 * a2 + a3 * a3;
        float pd = a0 * b0 + a1 * b1 + a2 * b2 + a3 * b3;
        #pragma unroll
        for (int off = 32; off > 0; off >>= 1) {
            sd += __shfl_xor(sd, off);
            pd += __shfl_xor(pd, off);
        }
        if (lane == 0) {
            const float Sc = S[row] - EXP2F(sd) - EXP2F(pd);
            wacc += pd * LN2 - LN2 * __log2f(Sc);
        }
    }
    __shared__ float bs[4];
    if (lane == 0) bs[wave] = wacc;
    __syncthreads();
    if (tid == 0) {
        atomicAdd(cell, bs[0] + bs[1] + bs[2] + bs[3]);
        __threadfence();
        const unsigned int old = atomicAdd(counter, 1u);
        if (old == gridDim.x - 1) {
            const float tot = atomicAdd(cell, 0.0f);   // device-scope read
            out[0] = -tot / (float)N;
        }
    }
}

// ---------------------------------------------------------------------------
extern "C" void kernel_launch(void* const* d_in, const int* in_sizes, int n_in,
                              void* d_out, int out_size, void* d_ws, size_t ws_size,
                              hipStream_t stream) {
    const float* a = (const float*)d_in[0];
    const float* b = (const float*)d_in[1];
    float* out = (float*)d_out;
    const int N = NROWS;

    char* ws = (char*)d_ws;
    unsigned short* en = (unsigned short*)ws;                  // 2N*D*2 = 4 MB
    float* S = (float*)(ws + (size_t)2 * N * DDIM * sizeof(unsigned short));
    float* cell = S + N;
    unsigned int* counter = (unsigned int*)(cell + 1);

    normalize_kernel<<<(2 * N) / 4, 256, 0, stream>>>(a, b, en, S, cell,
                                                      counter, N);
    simsum_kernel<<<dim3(N / 256, NJ), 256, 0, stream>>>((const short*)en, S);
    loss_kernel<<<64, 256, 0, stream>>>(en, S, cell, counter, out, N);
}